// Round 2
// baseline (1284.504 us; speedup 1.0000x reference)
//
#include <hip/hip_runtime.h>

#define S_NUM 7
#define NB 10
#define NEG_INF (-3.402823466e38f)

// ============================ prep kernels ============================

__global__ void normalize_dirs_kernel(const float* __restrict__ dirs, float* __restrict__ out, int M) {
  int m = blockIdx.x * blockDim.x + threadIdx.x;
  if (m >= M) return;
  float a = dirs[m], b = dirs[M + m], c = dirs[2 * M + m];
  float L = fmaxf(sqrtf(a * a + b * b + c * c), 1e-12f);
  out[m] = a / L; out[M + m] = b / L; out[2 * M + m] = c / L;
}

// out[c][r] = in[r*Cfull + c]  for c < Csub, r < R
__global__ void transpose_sub_kernel(const float* __restrict__ in, float* __restrict__ out,
                                     int R, int Cfull, int Csub) {
  int t = blockIdx.x * blockDim.x + threadIdx.x;
  if (t >= R * Csub) return;
  int r = t % R, c = t / R;
  out[(size_t)c * R + r] = in[(size_t)r * Cfull + c];
}

// ============================ KNN ============================
// One wave per query point. Per-lane sorted top-11 (static indices only),
// then 11 rounds of wave-wide u64-min extraction. Key = (ordered(dist) << 32) | j
// matches jax.lax.top_k(-dist) ordering incl. tie-break by lower index.
__global__ __launch_bounds__(256) void knn_kernel(const float* __restrict__ verts, int V, int bstride,
                                                  int* __restrict__ idx_out) {
  int wave = threadIdx.x >> 6;
  int lane = threadIdx.x & 63;
  int i = blockIdx.x * 4 + wave;
  int b = blockIdx.y;
  if (i >= V) return;
  const float* vb = verts + (size_t)b * bstride;
  float xi = vb[3 * i], yi = vb[3 * i + 1], zi = vb[3 * i + 2];
  float d2i = xi * xi + yi * yi + zi * zi;
  unsigned long long top[11];
#pragma unroll
  for (int t = 0; t < 11; ++t) top[t] = ~0ull;
  for (int j = lane; j < V; j += 64) {
    float xj = vb[3 * j], yj = vb[3 * j + 1], zj = vb[3 * j + 2];
    float d2j = xj * xj + yj * yj + zj * zj;
    float dt = xi * xj + yi * yj + zi * zj;
    float dist = (d2i + d2j) - 2.0f * dt;
    if (j == i) dist = -1.0f;  // self is exact-0 in ref; force it to sort first
    unsigned int fb = __float_as_uint(dist);
    fb ^= ((unsigned int)((int)fb >> 31)) | 0x80000000u;
    unsigned long long key = ((unsigned long long)fb << 32) | (unsigned int)j;
    if (key < top[10]) {
      top[10] = key;
#pragma unroll
      for (int t = 10; t > 0; --t) {
        if (top[t] < top[t - 1]) { unsigned long long tm = top[t]; top[t] = top[t - 1]; top[t - 1] = tm; }
      }
    }
  }
#pragma unroll 1
  for (int t = 0; t < 11; ++t) {
    unsigned long long m = top[0];
#pragma unroll
    for (int o = 32; o > 0; o >>= 1) {
      unsigned long long other = __shfl_xor(m, o, 64);
      m = (other < m) ? other : m;
    }
    if (top[0] == m) {  // unique key -> exactly one lane; pop head (static shift)
#pragma unroll
      for (int q = 0; q < 10; ++q) top[q] = top[q + 1];
      top[10] = ~0ull;
    }
    if (t >= 1 && lane == 0)
      idx_out[((size_t)b * V + i) * NB + (t - 1)] = (int)(m & 0xffffffffu);
  }
}

// ============================ GEMM (fp32, VALU) ============================
// C[M,N] = A[M,K] @ B[K,N] (+bias[N]) (+resid[row*N+col]) (+gterm[(row/rpb)*N+col]) (relu?)
// BM=64 BN=64 BK=32, 256 threads, 4x4 microtile, float4 LDS reads.
__global__ __launch_bounds__(256) void gemm_kernel(
    const float* __restrict__ A, const float* __restrict__ B,
    const float* __restrict__ bias, const float* __restrict__ gt,
    const float* __restrict__ resid, float* __restrict__ C,
    int M, int N, int K, int rpb, int relu) {
  __shared__ float As[32][68];  // [k][m], +4 pad keeps float4 align & spreads banks
  __shared__ float Bs[32][64];  // [k][n]
  int bm = blockIdx.x * 64;
  int bn = blockIdx.y * 64;
  int tid = threadIdx.x;
  int tx = tid & 15, ty = tid >> 4;
  float acc[4][4] = {};
  for (int k0 = 0; k0 < K; k0 += 32) {
#pragma unroll
    for (int l = 0; l < 2; ++l) {
      int f = tid + l * 256;           // 512 float4 of A tile
      int row = f >> 3, kq = f & 7;
      float4 a = *reinterpret_cast<const float4*>(&A[(size_t)(bm + row) * K + k0 + kq * 4]);
      As[kq * 4 + 0][row] = a.x; As[kq * 4 + 1][row] = a.y;
      As[kq * 4 + 2][row] = a.z; As[kq * 4 + 3][row] = a.w;
    }
#pragma unroll
    for (int l = 0; l < 2; ++l) {
      int f = tid + l * 256;           // 512 float4 of B tile
      int row = f >> 4, cq = f & 15;
      float4 v = *reinterpret_cast<const float4*>(&B[(size_t)(k0 + row) * N + bn + cq * 4]);
      *reinterpret_cast<float4*>(&Bs[row][cq * 4]) = v;
    }
    __syncthreads();
#pragma unroll
    for (int kk = 0; kk < 32; ++kk) {
      float4 av = *reinterpret_cast<const float4*>(&As[kk][ty * 4]);
      float4 bv = *reinterpret_cast<const float4*>(&Bs[kk][tx * 4]);
      float am[4] = {av.x, av.y, av.z, av.w};
      float bb[4] = {bv.x, bv.y, bv.z, bv.w};
#pragma unroll
      for (int i2 = 0; i2 < 4; ++i2)
#pragma unroll
        for (int j2 = 0; j2 < 4; ++j2)
          acc[i2][j2] = fmaf(am[i2], bb[j2], acc[i2][j2]);
    }
    __syncthreads();
  }
#pragma unroll
  for (int i2 = 0; i2 < 4; ++i2) {
    int row = bm + ty * 4 + i2;
    int col0 = bn + tx * 4;
    float4 v;
    float* vv = reinterpret_cast<float*>(&v);
#pragma unroll
    for (int j2 = 0; j2 < 4; ++j2) {
      float t = acc[i2][j2];
      int col = col0 + j2;
      if (bias)  t += bias[col];
      if (resid) t += resid[(size_t)row * N + col];
      if (gt)    t += gt[(row / rpb) * N + col];
      if (relu)  t = fmaxf(t, 0.0f);
      vv[j2] = t;
    }
    *reinterpret_cast<float4*>(&C[(size_t)row * N + col0]) = v;
  }
}

// ============================ surface layer 0 ============================
__global__ __launch_bounds__(128) void surface0_kernel(const float* __restrict__ verts,
    const int* __restrict__ idx, const float* __restrict__ ndirs,
    const float* __restrict__ ste0, float* __restrict__ feat) {
  __shared__ float dn[NB][3];
  int b = blockIdx.y, v = blockIdx.x;
  const float* vb = verts + (size_t)b * 4096 * 3;
  int tid = threadIdx.x;
  if (tid < NB) {
    int j = idx[((size_t)b * 4096 + v) * NB + tid];
    float dx = vb[3 * j] - vb[3 * v];
    float dy = vb[3 * j + 1] - vb[3 * v + 1];
    float dz = vb[3 * j + 2] - vb[3 * v + 2];
    float L = fmaxf(sqrtf(dx * dx + dy * dy + dz * dz), 1e-12f);
    dn[tid][0] = dx / L; dn[tid][1] = dy / L; dn[tid][2] = dz / L;
  }
  __syncthreads();
  int c = tid;
  float acc = vb[3 * v] * ste0[c * 3] + vb[3 * v + 1] * ste0[c * 3 + 1] + vb[3 * v + 2] * ste0[c * 3 + 2];
#pragma unroll
  for (int s = 0; s < S_NUM; ++s) {
    float w0 = ndirs[s * 128 + c], w1 = ndirs[896 + s * 128 + c], w2 = ndirs[1792 + s * 128 + c];
    float mx = NEG_INF;
#pragma unroll
    for (int n = 0; n < NB; ++n) {
      float th = fmaxf(dn[n][0] * w0 + dn[n][1] * w1 + dn[n][2] * w2, 0.0f);
      mx = fmaxf(mx, th);
    }
    acc += mx;
  }
  feat[((size_t)b * 4096 + v) * 128 + c] = acc;
}

// ============================ hs aggregate ============================
// feat[b,v,c] = fout[row,c] + fste[row,c] + sum_s max_n relu(dn.dirs_s)*fout[nbr, C+s*C+c]
template <int C>
__global__ void hs_kernel(const float* __restrict__ verts, int V,
                          const int* __restrict__ idx, const float* __restrict__ ndirs,
                          const float* __restrict__ fout, const float* __restrict__ fste,
                          float* __restrict__ feat) {
  __shared__ float dn[NB][3];
  __shared__ int nbr[NB];
  int b = blockIdx.y, v = blockIdx.x;
  const float* vb = verts + (size_t)b * 4096 * 3;  // v1/v2 are prefixes of each batch block
  int tid = threadIdx.x;
  if (tid < NB) {
    int j = idx[((size_t)b * V + v) * NB + tid];
    nbr[tid] = j;
    float dx = vb[3 * j] - vb[3 * v];
    float dy = vb[3 * j + 1] - vb[3 * v + 1];
    float dz = vb[3 * j + 2] - vb[3 * v + 2];
    float L = fmaxf(sqrtf(dx * dx + dy * dy + dz * dz), 1e-12f);
    dn[tid][0] = dx / L; dn[tid][1] = dy / L; dn[tid][2] = dz / L;
  }
  __syncthreads();
  int c = tid;
  size_t row = (size_t)b * V + v;
  float w0[S_NUM], w1[S_NUM], w2[S_NUM];
#pragma unroll
  for (int s = 0; s < S_NUM; ++s) {
    w0[s] = ndirs[s * C + c];
    w1[s] = ndirs[S_NUM * C + s * C + c];
    w2[s] = ndirs[2 * S_NUM * C + s * C + c];
  }
  float mx[S_NUM];
#pragma unroll
  for (int s = 0; s < S_NUM; ++s) mx[s] = NEG_INF;
  for (int n = 0; n < NB; ++n) {
    float d0 = dn[n][0], d1 = dn[n][1], d2 = dn[n][2];
    const float* fb = fout + ((size_t)b * V + nbr[n]) * (8 * C) + C + c;
#pragma unroll
    for (int s = 0; s < S_NUM; ++s) {
      float th = fmaxf(d0 * w0[s] + d1 * w1[s] + d2 * w2[s], 0.0f);
      mx[s] = fmaxf(mx[s], th * fb[(size_t)s * C]);
    }
  }
  float acc = fout[row * (8 * C) + c] + fste[row * C + c];
#pragma unroll
  for (int s = 0; s < S_NUM; ++s) acc += mx[s];
  feat[row * C + c] = acc;
}

// ============================ reductions / BN / pool / max ============================

__global__ void colsum_kernel(const float* __restrict__ x, double* __restrict__ sums,
                              int V, int C, int chunk) {
  int b = blockIdx.x, c = threadIdx.x;
  int r0 = blockIdx.y * chunk;
  int r1 = min(r0 + chunk, V);
  float s = 0.f;
  for (int r = r0; r < r1; ++r) s += x[((size_t)b * V + r) * C + c];
  atomicAdd(&sums[b * C + c], (double)s);
}

__global__ void gterm_kernel(const double* __restrict__ sums, const float* __restrict__ orl,
                             float* __restrict__ gt, int C, int O, double invV) {
  int b = blockIdx.x;
  int o = blockIdx.y * 64 + threadIdx.x;
  if (o >= O) return;
  float acc = 0.f;
  for (int c = 0; c < C; ++c)
    acc += (float)(sums[b * C + c] * invV) * orl[(size_t)o * (2 * C) + C + c];
  gt[b * O + o] = acc;
}

__global__ void bnstat_kernel(const float* __restrict__ x, double* __restrict__ stats,
                              int rows, int C, int chunk) {
  int c = threadIdx.x;
  int r0 = blockIdx.x * chunk;
  int r1 = min(r0 + chunk, rows);
  float s1 = 0.f, s2 = 0.f;
  for (int r = r0; r < r1; ++r) {
    float v = x[(size_t)r * C + c];
    s1 += v; s2 += v * v;
  }
  atomicAdd(&stats[c], (double)s1);
  atomicAdd(&stats[C + c], (double)s2);
}

__global__ void bnapply_kernel(const float* __restrict__ x, const double* __restrict__ stats,
                               const float* __restrict__ g, const float* __restrict__ bta,
                               float* __restrict__ y, int total, int C, double invN) {
  int i = blockIdx.x * blockDim.x + threadIdx.x;
  if (i >= total) return;
  int c = i % C;
  double m = stats[c] * invN;
  double var = stats[C + c] * invN - m * m;
  double inv = 1.0 / sqrt(var + 1e-5);
  float r = (float)(((double)x[i] - m) * inv) * g[c] + bta[c];
  y[i] = fmaxf(r, 0.0f);
}

template <int C>
__global__ void pool_kernel(const float* __restrict__ fm, const int* __restrict__ idx,
                            float* __restrict__ fp, int Vin) {
  int b = blockIdx.y, p = blockIdx.x, c = threadIdx.x;
  const int* ip = idx + ((size_t)b * Vin + p) * NB;
  float m = NEG_INF;
#pragma unroll
  for (int j = 0; j < 4; ++j)
    m = fmaxf(m, fm[((size_t)b * Vin + ip[j]) * C + c]);
  fp[((size_t)b * gridDim.x + p) * C + c] = m;
}

__global__ void finalmax_kernel(const float* __restrict__ fm4, float* __restrict__ out) {
  int b = blockIdx.x;
  int o = blockIdx.y * 256 + threadIdx.x;
  float m = NEG_INF;
  for (int v = 0; v < 256; ++v)
    m = fmaxf(m, fm4[((size_t)b * 256 + v) * 512 + o]);
  out[b * 512 + o] = m;
}

// ============================ host ============================

extern "C" void kernel_launch(void* const* d_in, const int* in_sizes, int n_in,
                              void* d_out, int out_size, void* d_ws, size_t ws_size,
                              hipStream_t stream) {
  const float* verts = (const float*)d_in[0];
  const float* dirs0 = (const float*)d_in[1];
  const float* ste0  = (const float*)d_in[2];
  const float* orl0  = (const float*)d_in[3];
  const float* w1    = (const float*)d_in[4];
  const float* b1    = (const float*)d_in[5];
  const float* dirs1 = (const float*)d_in[6];
  const float* ste1  = (const float*)d_in[7];
  const float* orl1  = (const float*)d_in[8];
  const float* bn1g  = (const float*)d_in[9];
  const float* bn1b  = (const float*)d_in[10];
  const float* w2    = (const float*)d_in[11];
  const float* b2    = (const float*)d_in[12];
  const float* dirs2 = (const float*)d_in[13];
  const float* ste2  = (const float*)d_in[14];
  const float* orl2  = (const float*)d_in[15];
  const float* bn2g  = (const float*)d_in[16];
  const float* bn2b  = (const float*)d_in[17];
  const float* w3    = (const float*)d_in[18];
  const float* b3    = (const float*)d_in[19];
  const float* dirs3 = (const float*)d_in[20];
  const float* ste3  = (const float*)d_in[21];
  const float* orl3  = (const float*)d_in[22];
  const float* bn3g  = (const float*)d_in[23];
  const float* bn3b  = (const float*)d_in[24];
  const float* w4    = (const float*)d_in[25];
  const float* b4    = (const float*)d_in[26];
  const float* dirs4 = (const float*)d_in[27];
  const float* ste4  = (const float*)d_in[28];
  const float* orl4  = (const float*)d_in[29];

  char* base = (char*)d_ws;
  size_t off = 0;
  auto alloc = [&](size_t bytes) -> void* {
    off = (off + 255) & ~(size_t)255;
    void* p = base + off;
    off += bytes;
    return p;
  };

  float* nd0  = (float*)alloc(3 * 896 * 4);
  float* nd1  = (float*)alloc(3 * 896 * 4);
  float* nd2  = (float*)alloc(3 * 1792 * 4);
  float* nd3  = (float*)alloc(3 * 1792 * 4);
  float* nd4  = (float*)alloc(3 * 3584 * 4);
  float* sT1  = (float*)alloc(128 * 128 * 4);
  float* sT2  = (float*)alloc(128 * 256 * 4);
  float* sT3  = (float*)alloc(256 * 256 * 4);
  float* sT4  = (float*)alloc(256 * 512 * 4);
  float* oA0  = (float*)alloc(128 * 128 * 4);
  float* oA1  = (float*)alloc(128 * 128 * 4);
  float* oA2  = (float*)alloc(256 * 256 * 4);
  float* oA3  = (float*)alloc(256 * 256 * 4);
  float* oA4  = (float*)alloc(512 * 512 * 4);
  int*   idx0 = (int*)alloc((size_t)4 * 4096 * NB * 4);
  int*   idx1 = (int*)alloc((size_t)4 * 1024 * NB * 4);
  int*   idx2 = (int*)alloc((size_t)4 * 256 * NB * 4);
  double* gsum  = (double*)alloc(4 * 512 * 8);
  float*  gterm = (float*)alloc(4 * 512 * 4);
  double* stats = (double*)alloc(2 * 256 * 8);
  // big regions (reused across layers; lifetimes verified)
  float* Rfout = (float*)alloc((size_t)16384 * 1024 * 4);  // fout1/2/3/4
  float* Rfeat = (float*)alloc((size_t)16384 * 128 * 4);   // feat0..feat4
  float* Rtmp  = (float*)alloc((size_t)16384 * 128 * 4);   // fm0, tmp1..3, fm4
  float* Rfste = (float*)alloc((size_t)16384 * 128 * 4);   // fste1..4
  float* Rfm   = (float*)alloc((size_t)16384 * 128 * 4);   // fm1..3
  float* Rfp   = (float*)alloc((size_t)4 * 1024 * 128 * 4);// fp1, fp2
  (void)in_sizes; (void)n_in; (void)out_size; (void)ws_size;

  auto gemm = [&](const float* A, const float* B, const float* bias, const float* gt,
                  const float* resid, float* C, int M, int N, int K, int rpb, int relu) {
    gemm_kernel<<<dim3(M / 64, N / 64), 256, 0, stream>>>(A, B, bias, gt, resid, C, M, N, K, rpb ? rpb : 1, relu);
  };

  // ---- prep: normalized dirs, transposed small mats ----
  normalize_dirs_kernel<<<(896 + 255) / 256, 256, 0, stream>>>(dirs0, nd0, 896);
  normalize_dirs_kernel<<<(896 + 255) / 256, 256, 0, stream>>>(dirs1, nd1, 896);
  normalize_dirs_kernel<<<(1792 + 255) / 256, 256, 0, stream>>>(dirs2, nd2, 1792);
  normalize_dirs_kernel<<<(1792 + 255) / 256, 256, 0, stream>>>(dirs3, nd3, 1792);
  normalize_dirs_kernel<<<(3584 + 255) / 256, 256, 0, stream>>>(dirs4, nd4, 3584);
  transpose_sub_kernel<<<(128 * 128 + 255) / 256, 256, 0, stream>>>(ste1, sT1, 128, 128, 128);
  transpose_sub_kernel<<<(256 * 128 + 255) / 256, 256, 0, stream>>>(ste2, sT2, 256, 128, 128);
  transpose_sub_kernel<<<(256 * 256 + 255) / 256, 256, 0, stream>>>(ste3, sT3, 256, 256, 256);
  transpose_sub_kernel<<<(512 * 256 + 255) / 256, 256, 0, stream>>>(ste4, sT4, 512, 256, 256);
  transpose_sub_kernel<<<(128 * 128 + 255) / 256, 256, 0, stream>>>(orl0, oA0, 128, 256, 128);
  transpose_sub_kernel<<<(128 * 128 + 255) / 256, 256, 0, stream>>>(orl1, oA1, 128, 256, 128);
  transpose_sub_kernel<<<(256 * 256 + 255) / 256, 256, 0, stream>>>(orl2, oA2, 256, 512, 256);
  transpose_sub_kernel<<<(256 * 256 + 255) / 256, 256, 0, stream>>>(orl3, oA3, 256, 512, 256);
  transpose_sub_kernel<<<(512 * 512 + 255) / 256, 256, 0, stream>>>(orl4, oA4, 512, 1024, 512);

  const int VSTRIDE = 4096 * 3;

  // ---- KNN (shared: layers 0+1 and pool1 use idx0; layers 2+3 and pool2 use idx1) ----
  knn_kernel<<<dim3(4096 / 4, 4), 256, 0, stream>>>(verts, 4096, VSTRIDE, idx0);

  // ---- layer 0: surface ----
  surface0_kernel<<<dim3(4096, 4), 128, 0, stream>>>(verts, idx0, nd0, ste0, Rfeat);
  hipMemsetAsync(gsum, 0, 4 * 512 * 8, stream);
  colsum_kernel<<<dim3(4, 32), 128, 0, stream>>>(Rfeat, gsum, 4096, 128, 128);
  gterm_kernel<<<dim3(4, 2), 64, 0, stream>>>(gsum, orl0, gterm, 128, 128, 1.0 / 4096);
  gemm(Rfeat, oA0, nullptr, gterm, Rfeat, Rtmp, 16384, 128, 128, 4096, 1);  // fm0 = relu(ORL0)

  // ---- layer 1 ----
  gemm(Rtmp, w1, b1, nullptr, nullptr, Rfout, 16384, 1024, 128, 0, 0);      // fout1
  gemm(Rtmp, sT1, nullptr, nullptr, nullptr, Rfste, 16384, 128, 128, 0, 0); // fste1
  hs_kernel<128><<<dim3(4096, 4), 128, 0, stream>>>(verts, 4096, idx0, nd1, Rfout, Rfste, Rfeat);
  hipMemsetAsync(gsum, 0, 4 * 512 * 8, stream);
  colsum_kernel<<<dim3(4, 32), 128, 0, stream>>>(Rfeat, gsum, 4096, 128, 128);
  gterm_kernel<<<dim3(4, 2), 64, 0, stream>>>(gsum, orl1, gterm, 128, 128, 1.0 / 4096);
  gemm(Rfeat, oA1, nullptr, gterm, Rfeat, Rtmp, 16384, 128, 128, 4096, 0);  // tmp1 = ORL1
  hipMemsetAsync(stats, 0, 2 * 256 * 8, stream);
  bnstat_kernel<<<128, 128, 0, stream>>>(Rtmp, stats, 16384, 128, 128);
  bnapply_kernel<<<(16384 * 128 + 255) / 256, 256, 0, stream>>>(Rtmp, stats, bn1g, bn1b, Rfm, 16384 * 128, 128, 1.0 / 16384);
  pool_kernel<128><<<dim3(1024, 4), 128, 0, stream>>>(Rfm, idx0, Rfp, 4096);  // fp1
  knn_kernel<<<dim3(1024 / 4, 4), 256, 0, stream>>>(verts, 1024, VSTRIDE, idx1);

  // ---- layer 2 ----
  gemm(Rfp, w2, b2, nullptr, nullptr, Rfout, 4096, 2048, 128, 0, 0);        // fout2
  gemm(Rfp, sT2, nullptr, nullptr, nullptr, Rfste, 4096, 256, 128, 0, 0);   // fste2
  hs_kernel<256><<<dim3(1024, 4), 256, 0, stream>>>(verts, 1024, idx1, nd2, Rfout, Rfste, Rfeat);
  hipMemsetAsync(gsum, 0, 4 * 512 * 8, stream);
  colsum_kernel<<<dim3(4, 8), 256, 0, stream>>>(Rfeat, gsum, 1024, 256, 128);
  gterm_kernel<<<dim3(4, 4), 64, 0, stream>>>(gsum, orl2, gterm, 256, 256, 1.0 / 1024);
  gemm(Rfeat, oA2, nullptr, gterm, Rfeat, Rtmp, 4096, 256, 256, 1024, 0);   // tmp2
  hipMemsetAsync(stats, 0, 2 * 256 * 8, stream);
  bnstat_kernel<<<32, 256, 0, stream>>>(Rtmp, stats, 4096, 256, 128);
  bnapply_kernel<<<(4096 * 256 + 255) / 256, 256, 0, stream>>>(Rtmp, stats, bn2g, bn2b, Rfm, 4096 * 256, 256, 1.0 / 4096);

  // ---- layer 3 ----
  gemm(Rfm, w3, b3, nullptr, nullptr, Rfout, 4096, 2048, 256, 0, 0);        // fout3
  gemm(Rfm, sT3, nullptr, nullptr, nullptr, Rfste, 4096, 256, 256, 0, 0);   // fste3
  hs_kernel<256><<<dim3(1024, 4), 256, 0, stream>>>(verts, 1024, idx1, nd3, Rfout, Rfste, Rfeat);
  hipMemsetAsync(gsum, 0, 4 * 512 * 8, stream);
  colsum_kernel<<<dim3(4, 8), 256, 0, stream>>>(Rfeat, gsum, 1024, 256, 128);
  gterm_kernel<<<dim3(4, 4), 64, 0, stream>>>(gsum, orl3, gterm, 256, 256, 1.0 / 1024);
  gemm(Rfeat, oA3, nullptr, gterm, Rfeat, Rtmp, 4096, 256, 256, 1024, 0);   // tmp3
  hipMemsetAsync(stats, 0, 2 * 256 * 8, stream);
  bnstat_kernel<<<32, 256, 0, stream>>>(Rtmp, stats, 4096, 256, 128);
  bnapply_kernel<<<(4096 * 256 + 255) / 256, 256, 0, stream>>>(Rtmp, stats, bn3g, bn3b, Rfm, 4096 * 256, 256, 1.0 / 4096);
  pool_kernel<256><<<dim3(256, 4), 256, 0, stream>>>(Rfm, idx1, Rfp, 1024); // fp2
  knn_kernel<<<dim3(256 / 4, 4), 256, 0, stream>>>(verts, 256, VSTRIDE, idx2);

  // ---- layer 4 ----
  gemm(Rfp, w4, b4, nullptr, nullptr, Rfout, 1024, 4096, 256, 0, 0);        // fout4
  gemm(Rfp, sT4, nullptr, nullptr, nullptr, Rfste, 1024, 512, 256, 0, 0);   // fste4
  hs_kernel<512><<<dim3(256, 4), 512, 0, stream>>>(verts, 256, idx2, nd4, Rfout, Rfste, Rfeat);
  hipMemsetAsync(gsum, 0, 4 * 512 * 8, stream);
  colsum_kernel<<<dim3(4, 2), 512, 0, stream>>>(Rfeat, gsum, 256, 512, 128);
  gterm_kernel<<<dim3(4, 8), 64, 0, stream>>>(gsum, orl4, gterm, 512, 512, 1.0 / 256);
  gemm(Rfeat, oA4, nullptr, gterm, Rfeat, Rtmp, 1024, 512, 512, 256, 0);    // fm4

  finalmax_kernel<<<dim3(4, 2), 256, 0, stream>>>(Rtmp, (float*)d_out);
}